// Round 2
// baseline (1594.017 us; speedup 1.0000x reference)
//
#include <hip/hip_runtime.h>

// B=8, C=512, CH=256, R=64, H=W=64, N=4096. All inputs/outputs fp32.

// ---------------------------------------------------------------------------
// Kernel 1: fold q/k projections into the input convs.
// Wqk[j][0:512]   = sw_g[r,:] @ wt[rows cbase..cbase+255][:]   (j = g*64+r)
// Wqk[j][512:1024]= sw_g[r,:] @ wb[...]
// bqk[j] = sw_g[r,:] @ (bt+bb)[cbase:...] + sb_g[r]
// groups g: 0=q1(s_w1), 1=k1(s_w2), 2=q2(c_wq), 3=k2(c_wk)
// ---------------------------------------------------------------------------
__global__ __launch_bounds__(256) void k_combine_qk(
    const float* __restrict__ wt, const float* __restrict__ bt,
    const float* __restrict__ wb, const float* __restrict__ bb,
    const float* __restrict__ s_w1, const float* __restrict__ s_b1,
    const float* __restrict__ s_w2, const float* __restrict__ s_b2,
    const float* __restrict__ c_wq, const float* __restrict__ c_bq,
    const float* __restrict__ c_wk, const float* __restrict__ c_bk,
    float* __restrict__ Wqk, float* __restrict__ bqk) {
  int j = blockIdx.x;            // 0..255
  int g = j >> 6, r = j & 63;
  const float* sw; const float* sb;
  if (g == 0)      { sw = s_w1; sb = s_b1; }
  else if (g == 1) { sw = s_w2; sb = s_b2; }
  else if (g == 2) { sw = c_wq; sb = c_bq; }
  else             { sw = c_wk; sb = c_bk; }
  int cbase = (g < 2) ? 0 : 256;

  __shared__ float swr[256];
  __shared__ float red[256];
  int t = threadIdx.x;
  swr[t] = sw[r * 256 + t];
  __syncthreads();

  float a0 = 0.f, a1 = 0.f, a2 = 0.f, a3 = 0.f;
  for (int c = 0; c < 256; ++c) {
    float a = swr[c];
    int row = (cbase + c) * 512;
    a0 += a * wt[row + t];
    a1 += a * wt[row + 256 + t];
    a2 += a * wb[row + t];
    a3 += a * wb[row + 256 + t];
  }
  Wqk[j * 1024 + t]       = a0;
  Wqk[j * 1024 + 256 + t] = a1;
  Wqk[j * 1024 + 512 + t] = a2;
  Wqk[j * 1024 + 768 + t] = a3;

  red[t] = swr[t] * (bt[cbase + t] + bb[cbase + t]);
  __syncthreads();
  for (int s = 128; s > 0; s >>= 1) {
    if (t < s) red[t] += red[t + s];
    __syncthreads();
  }
  if (t == 0) bqk[j] = red[0] + sb[r];
}

// ---------------------------------------------------------------------------
// Kernel 2: fold s_wo / c_wo into the final conv.
// Wf[o][r<64] = f_w[o,0:256]@s_wo[:,r];  Wf[o][64+r] = f_w[o,256:512]@c_wo[:,r]
// bfb[o] = f_w[o,0:256]@s_bo + f_w[o,256:]@c_bo + f_b[o]
// ---------------------------------------------------------------------------
__global__ __launch_bounds__(128) void k_combine_f(
    const float* __restrict__ f_w, const float* __restrict__ f_b,
    const float* __restrict__ s_wo, const float* __restrict__ s_bo,
    const float* __restrict__ c_wo, const float* __restrict__ c_bo,
    float* __restrict__ Wf, float* __restrict__ bfb) {
  int o = blockIdx.x;   // 0..511
  int t = threadIdx.x;  // 0..127
  __shared__ float fwr[512];
  __shared__ float red[128];
  for (int i = t; i < 512; i += 128) fwr[i] = f_w[o * 512 + i];
  __syncthreads();

  float acc = 0.f;
  if (t < 64) {
    for (int c = 0; c < 256; ++c) acc += fwr[c] * s_wo[c * 64 + t];
  } else {
    int rr = t - 64;
    for (int c = 0; c < 256; ++c) acc += fwr[256 + c] * c_wo[c * 64 + rr];
  }
  Wf[o * 128 + t] = acc;

  red[t] = fwr[t] * s_bo[t] + fwr[t + 128] * s_bo[t + 128]
         + fwr[256 + t] * c_bo[t] + fwr[384 + t] * c_bo[t + 128];
  __syncthreads();
  for (int s = 64; s > 0; s >>= 1) {
    if (t < s) red[t] += red[t + s];
    __syncthreads();
  }
  if (t == 0) bfb[o] = red[0] + f_b[o];
}

// ---------------------------------------------------------------------------
// Kernel 3: qk[b][j][n] = sum_k Wqk[j][k] * {top|bottom}[b][k][n] + bqk[j]
// M=256, K=1024 (512 top + 512 bottom), N=4096 per batch.
// Tile: 64 j x 128 n, K-chunk 32. Thread: 8 j x 4 n.
// ---------------------------------------------------------------------------
__global__ __launch_bounds__(256) void k_gemm_qk(
    const float* __restrict__ top, const float* __restrict__ bot,
    const float* __restrict__ Wqk, const float* __restrict__ bqk,
    float* __restrict__ qk) {
  int b = blockIdx.z, j0 = blockIdx.y * 64, n0 = blockIdx.x * 128;
  __shared__ float As[32][64];
  __shared__ float Xs[32][128];
  int t = threadIdx.x;
  int jg = t >> 5, nt = t & 31;
  float acc[8][4];
#pragma unroll
  for (int q = 0; q < 8; ++q)
#pragma unroll
    for (int p = 0; p < 4; ++p) acc[q][p] = 0.f;

  for (int kc = 0; kc < 1024; kc += 32) {
    __syncthreads();
#pragma unroll
    for (int i = t; i < 2048; i += 256) {
      int jl = i >> 5, kk = i & 31;
      As[kk][jl] = Wqk[(j0 + jl) * 1024 + kc + kk];
    }
    const float* src = (kc < 512) ? top : bot;
    int c0 = (kc < 512) ? kc : kc - 512;
#pragma unroll
    for (int i = t; i < 1024; i += 256) {
      int kk = i >> 5, w = i & 31;
      float4 v = *reinterpret_cast<const float4*>(
          src + (size_t)(b * 512 + c0 + kk) * 4096 + n0 + w * 4);
      *reinterpret_cast<float4*>(&Xs[kk][w * 4]) = v;
    }
    __syncthreads();
#pragma unroll
    for (int kk = 0; kk < 32; ++kk) {
      float4 a0 = *reinterpret_cast<const float4*>(&As[kk][jg * 8]);
      float4 a1 = *reinterpret_cast<const float4*>(&As[kk][jg * 8 + 4]);
      float4 bx = *reinterpret_cast<const float4*>(&Xs[kk][nt * 4]);
      float av[8] = {a0.x, a0.y, a0.z, a0.w, a1.x, a1.y, a1.z, a1.w};
      float bv[4] = {bx.x, bx.y, bx.z, bx.w};
#pragma unroll
      for (int q = 0; q < 8; ++q)
#pragma unroll
        for (int p = 0; p < 4; ++p) acc[q][p] += av[q] * bv[p];
    }
  }
#pragma unroll
  for (int q = 0; q < 8; ++q) {
    int j = j0 + jg * 8 + q;
    float bias = bqk[j];
    float4 v = make_float4(acc[q][0] + bias, acc[q][1] + bias,
                           acc[q][2] + bias, acc[q][3] + bias);
    *reinterpret_cast<float4*>(&qk[(size_t)(b * 256 + j) * 4096 + n0 + nt * 4]) = v;
  }
}

// ---------------------------------------------------------------------------
// Kernel 4: spatial softmax denominators.
// s[n,m] = sum_r q1[r,n]*k1[r,m];  dinv[b,n] = 1 / sum_m exp(s[n,m])
// Scores are small (|s|<~3 by construction) -> no max-subtraction needed.
// ---------------------------------------------------------------------------
__global__ __launch_bounds__(256) void k_sp_stats(
    const float* __restrict__ qk, float* __restrict__ dinv) {
  int b = blockIdx.y, n0 = blockIdx.x * 64;
  const float* q1 = qk + (size_t)(b * 256) * 4096;
  const float* k1 = qk + (size_t)(b * 256 + 64) * 4096;
  __shared__ float Qt[64][64];
  __shared__ float Km[64][64];
  __shared__ float red[64][16];
  int t = threadIdx.x;
  int ti = t >> 4, tj = t & 15;

  for (int i = t; i < 4096; i += 256) {
    int r = i >> 6, n = i & 63;
    Qt[r][n] = q1[(size_t)r * 4096 + n0 + n];
  }
  float dsum[4] = {0.f, 0.f, 0.f, 0.f};

  for (int mt = 0; mt < 64; ++mt) {
    int m0 = mt * 64;
    __syncthreads();
    for (int i = t; i < 4096; i += 256) {
      int r = i >> 6, m = i & 63;
      Km[r][m] = k1[(size_t)r * 4096 + m0 + m];
    }
    __syncthreads();
    float s[4][4] = {};
#pragma unroll
    for (int r = 0; r < 64; ++r) {
      float4 qv = *reinterpret_cast<const float4*>(&Qt[r][ti * 4]);
      float4 kv = *reinterpret_cast<const float4*>(&Km[r][tj * 4]);
      float qa[4] = {qv.x, qv.y, qv.z, qv.w};
      float ka[4] = {kv.x, kv.y, kv.z, kv.w};
#pragma unroll
      for (int i = 0; i < 4; ++i)
#pragma unroll
        for (int jx = 0; jx < 4; ++jx) s[i][jx] += qa[i] * ka[jx];
    }
#pragma unroll
    for (int i = 0; i < 4; ++i)
#pragma unroll
      for (int jx = 0; jx < 4; ++jx) dsum[i] += __expf(s[i][jx]);
  }

  __syncthreads();
#pragma unroll
  for (int i = 0; i < 4; ++i) red[ti * 4 + i][tj] = dsum[i];
  __syncthreads();
  if (t < 64) {
    float sum = 0.f;
#pragma unroll
    for (int u = 0; u < 16; ++u) sum += red[t][u];
    dinv[(size_t)b * 4096 + n0 + t] = 1.0f / sum;
  }
}

// ---------------------------------------------------------------------------
// Kernel 5: channel attention partial scores.
// part[b][ch][r][s] = sum_{n in chunk ch} q2[r,n]*k2[s,n]   (8 chunks of 512)
// ---------------------------------------------------------------------------
__global__ __launch_bounds__(256) void k_ch_scores(
    const float* __restrict__ qk, float* __restrict__ part) {
  int b = blockIdx.y, ch = blockIdx.x;
  const float* q2 = qk + (size_t)(b * 256 + 128) * 4096;
  const float* k2 = qk + (size_t)(b * 256 + 192) * 4096;
  __shared__ float Qs[64][65];
  __shared__ float Ks[64][65];
  int t = threadIdx.x, ti = t >> 4, tj = t & 15;
  float acc[4][4] = {};

  for (int sub = 0; sub < 8; ++sub) {
    int n0 = ch * 512 + sub * 64;
    __syncthreads();
    for (int i = t; i < 4096; i += 256) {
      int r = i >> 6, n = i & 63;
      Qs[r][n] = q2[(size_t)r * 4096 + n0 + n];
      Ks[r][n] = k2[(size_t)r * 4096 + n0 + n];
    }
    __syncthreads();
#pragma unroll
    for (int n = 0; n < 64; ++n) {
      float qa[4], ka[4];
#pragma unroll
      for (int i = 0; i < 4; ++i) qa[i] = Qs[ti * 4 + i][n];
#pragma unroll
      for (int jx = 0; jx < 4; ++jx) ka[jx] = Ks[tj * 4 + jx][n];
#pragma unroll
      for (int i = 0; i < 4; ++i)
#pragma unroll
        for (int jx = 0; jx < 4; ++jx) acc[i][jx] += qa[i] * ka[jx];
    }
  }
#pragma unroll
  for (int i = 0; i < 4; ++i)
#pragma unroll
    for (int jx = 0; jx < 4; ++jx)
      part[(size_t)(b * 8 + ch) * 4096 + (ti * 4 + i) * 64 + tj * 4 + jx] = acc[i][jx];
}

// ---------------------------------------------------------------------------
// Kernel 6: reduce partials + row softmax -> attn2[b][r][s]
// ---------------------------------------------------------------------------
__global__ __launch_bounds__(64) void k_ch_softmax(
    const float* __restrict__ part, float* __restrict__ attn2) {
  int b = blockIdx.x, r = threadIdx.x;
  float v[64];
  float mx = -1e30f;
#pragma unroll
  for (int s = 0; s < 64; ++s) {
    float sum = 0.f;
#pragma unroll
    for (int c = 0; c < 8; ++c)
      sum += part[(size_t)(b * 8 + c) * 4096 + r * 64 + s];
    v[s] = sum;
    mx = fmaxf(mx, sum);
  }
  float den = 0.f;
#pragma unroll
  for (int s = 0; s < 64; ++s) { v[s] = __expf(v[s] - mx); den += v[s]; }
  float inv = 1.0f / den;
#pragma unroll
  for (int s = 0; s < 64; ++s)
    attn2[(size_t)b * 4096 + r * 64 + s] = v[s] * inv;
}

// ---------------------------------------------------------------------------
// Kernel 7: cpre[b][r][n] = sum_s attn2[r,s] * k2[s,n]
// ---------------------------------------------------------------------------
__global__ __launch_bounds__(256) void k_ch_apply(
    const float* __restrict__ qk, const float* __restrict__ attn2,
    float* __restrict__ cpre) {
  int b = blockIdx.y;
  int n = blockIdx.x * 256 + threadIdx.x;
  const float* k2 = qk + (size_t)(b * 256 + 192) * 4096;
  __shared__ float As[64][64];
  int t = threadIdx.x;
  for (int i = t; i < 4096; i += 256) As[i >> 6][i & 63] = attn2[(size_t)b * 4096 + i];
  __syncthreads();

  float acc[64];
#pragma unroll
  for (int r = 0; r < 64; ++r) acc[r] = 0.f;
  for (int s4 = 0; s4 < 64; s4 += 4) {
    float kv0 = k2[(size_t)(s4 + 0) * 4096 + n];
    float kv1 = k2[(size_t)(s4 + 1) * 4096 + n];
    float kv2 = k2[(size_t)(s4 + 2) * 4096 + n];
    float kv3 = k2[(size_t)(s4 + 3) * 4096 + n];
#pragma unroll
    for (int r = 0; r < 64; ++r) {
      float4 w = *reinterpret_cast<const float4*>(&As[r][s4]);
      acc[r] += w.x * kv0 + w.y * kv1 + w.z * kv2 + w.w * kv3;
    }
  }
#pragma unroll
  for (int r = 0; r < 64; ++r)
    cpre[(size_t)(b * 64 + r) * 4096 + n] = acc[r];
}

// ---------------------------------------------------------------------------
// Kernel 8: spatial apply (the big one).
// spre[b][r][m] = sum_n k1[r,n] * exp(s[n,m]) * dinv[n]
// ---------------------------------------------------------------------------
__global__ __launch_bounds__(256) void k_sp_apply(
    const float* __restrict__ qk, const float* __restrict__ dinv,
    float* __restrict__ spre) {
  int b = blockIdx.y, m0 = blockIdx.x * 64;
  const float* q1 = qk + (size_t)(b * 256) * 4096;
  const float* k1 = qk + (size_t)(b * 256 + 64) * 4096;
  __shared__ float Km[64][64];
  __shared__ float Qn[64][64];
  __shared__ float Kn[64][65];   // padded: phase-2 scalar reads conflict-free
  __shared__ float Wt[64][64];
  __shared__ float Dv[64];
  int t = threadIdx.x, ti = t >> 4, tj = t & 15;

  for (int i = t; i < 4096; i += 256) {
    int r = i >> 6, m = i & 63;
    Km[r][m] = k1[(size_t)r * 4096 + m0 + m];
  }
  float acc[4][4] = {};

  for (int ntile = 0; ntile < 64; ++ntile) {
    int n0 = ntile * 64;
    __syncthreads();
    for (int i = t; i < 4096; i += 256) {
      int r = i >> 6, n = i & 63;
      Qn[r][n] = q1[(size_t)r * 4096 + n0 + n];
      Kn[r][n] = k1[(size_t)r * 4096 + n0 + n];
    }
    if (t < 64) Dv[t] = dinv[(size_t)b * 4096 + n0 + t];
    __syncthreads();

    float s[4][4] = {};
#pragma unroll
    for (int r = 0; r < 64; ++r) {
      float4 qv = *reinterpret_cast<const float4*>(&Qn[r][ti * 4]);
      float4 kv = *reinterpret_cast<const float4*>(&Km[r][tj * 4]);
      float qa[4] = {qv.x, qv.y, qv.z, qv.w};
      float ka[4] = {kv.x, kv.y, kv.z, kv.w};
#pragma unroll
      for (int i = 0; i < 4; ++i)
#pragma unroll
        for (int jx = 0; jx < 4; ++jx) s[i][jx] += qa[i] * ka[jx];
    }
#pragma unroll
    for (int i = 0; i < 4; ++i) {
      float dv = Dv[ti * 4 + i];
#pragma unroll
      for (int jx = 0; jx < 4; ++jx)
        Wt[ti * 4 + i][tj * 4 + jx] = __expf(s[i][jx]) * dv;
    }
    __syncthreads();

#pragma unroll
    for (int n = 0; n < 64; ++n) {
      float4 wv = *reinterpret_cast<const float4*>(&Wt[n][tj * 4]);
      float ka0 = Kn[ti * 4 + 0][n];
      float ka1 = Kn[ti * 4 + 1][n];
      float ka2 = Kn[ti * 4 + 2][n];
      float ka3 = Kn[ti * 4 + 3][n];
      acc[0][0] += ka0 * wv.x; acc[0][1] += ka0 * wv.y; acc[0][2] += ka0 * wv.z; acc[0][3] += ka0 * wv.w;
      acc[1][0] += ka1 * wv.x; acc[1][1] += ka1 * wv.y; acc[1][2] += ka1 * wv.z; acc[1][3] += ka1 * wv.w;
      acc[2][0] += ka2 * wv.x; acc[2][1] += ka2 * wv.y; acc[2][2] += ka2 * wv.z; acc[2][3] += ka2 * wv.w;
      acc[3][0] += ka3 * wv.x; acc[3][1] += ka3 * wv.y; acc[3][2] += ka3 * wv.z; acc[3][3] += ka3 * wv.w;
    }
  }

#pragma unroll
  for (int i = 0; i < 4; ++i) {
    float4 v = make_float4(acc[i][0], acc[i][1], acc[i][2], acc[i][3]);
    *reinterpret_cast<float4*>(
        &spre[(size_t)(b * 64 + ti * 4 + i) * 4096 + m0 + tj * 4]) = v;
  }
}

// ---------------------------------------------------------------------------
// Kernel 9: final fused conv.
// out[b][o][n] = Wf[o][0:64]@spre[b][:][n] + Wf[o][64:128]@cpre[b][:][n] + bfb[o]
// ---------------------------------------------------------------------------
__global__ __launch_bounds__(256) void k_final(
    const float* __restrict__ spre, const float* __restrict__ cpre,
    const float* __restrict__ Wf, const float* __restrict__ bfb,
    float* __restrict__ out) {
  int b = blockIdx.z, o0 = blockIdx.y * 64, n0 = blockIdx.x * 128;
  __shared__ float As[32][64];
  __shared__ float Xs[32][128];
  int t = threadIdx.x, og = t >> 5, nt = t & 31;
  float acc[8][4];
#pragma unroll
  for (int q = 0; q < 8; ++q)
#pragma unroll
    for (int p = 0; p < 4; ++p) acc[q][p] = 0.f;

  for (int kc = 0; kc < 128; kc += 32) {
    __syncthreads();
#pragma unroll
    for (int i = t; i < 2048; i += 256) {
      int ol = i >> 5, kk = i & 31;
      As[kk][ol] = Wf[(o0 + ol) * 128 + kc + kk];
    }
    const float* src = (kc < 64) ? spre : cpre;
    int r0 = (kc < 64) ? kc : kc - 64;
#pragma unroll
    for (int i = t; i < 1024; i += 256) {
      int kk = i >> 5, w = i & 31;
      float4 v = *reinterpret_cast<const float4*>(
          src + (size_t)(b * 64 + r0 + kk) * 4096 + n0 + w * 4);
      *reinterpret_cast<float4*>(&Xs[kk][w * 4]) = v;
    }
    __syncthreads();
#pragma unroll
    for (int kk = 0; kk < 32; ++kk) {
      float4 a0 = *reinterpret_cast<const float4*>(&As[kk][og * 8]);
      float4 a1 = *reinterpret_cast<const float4*>(&As[kk][og * 8 + 4]);
      float4 bx = *reinterpret_cast<const float4*>(&Xs[kk][nt * 4]);
      float av[8] = {a0.x, a0.y, a0.z, a0.w, a1.x, a1.y, a1.z, a1.w};
      float bv[4] = {bx.x, bx.y, bx.z, bx.w};
#pragma unroll
      for (int q = 0; q < 8; ++q)
#pragma unroll
        for (int p = 0; p < 4; ++p) acc[q][p] += av[q] * bv[p];
    }
  }
#pragma unroll
  for (int q = 0; q < 8; ++q) {
    int o = o0 + og * 8 + q;
    float bias = bfb[o];
    float4 v = make_float4(acc[q][0] + bias, acc[q][1] + bias,
                           acc[q][2] + bias, acc[q][3] + bias);
    *reinterpret_cast<float4*>(&out[(size_t)(b * 512 + o) * 4096 + n0 + nt * 4]) = v;
  }
}

// ---------------------------------------------------------------------------
extern "C" void kernel_launch(void* const* d_in, const int* in_sizes, int n_in,
                              void* d_out, int out_size, void* d_ws, size_t ws_size,
                              hipStream_t stream) {
  const float* top  = (const float*)d_in[0];
  const float* bot  = (const float*)d_in[1];
  const float* wt   = (const float*)d_in[2];
  const float* bt   = (const float*)d_in[3];
  const float* wb   = (const float*)d_in[4];
  const float* bb   = (const float*)d_in[5];
  const float* s_w1 = (const float*)d_in[6];
  const float* s_b1 = (const float*)d_in[7];
  const float* s_w2 = (const float*)d_in[8];
  const float* s_b2 = (const float*)d_in[9];
  const float* s_wo = (const float*)d_in[10];
  const float* s_bo = (const float*)d_in[11];
  const float* c_wq = (const float*)d_in[12];
  const float* c_bq = (const float*)d_in[13];
  const float* c_wk = (const float*)d_in[14];
  const float* c_bk = (const float*)d_in[15];
  const float* c_wo = (const float*)d_in[16];
  const float* c_bo = (const float*)d_in[17];
  const float* f_w  = (const float*)d_in[18];
  const float* f_b  = (const float*)d_in[19];
  float* out = (float*)d_out;

  // qk [8][256][4096] fp32 = 32 MB lives in d_out (64 MB); k_final fully
  // overwrites d_out afterwards and no longer reads qk.
  float* qk = (float*)d_out;

  char* ws = (char*)d_ws;   // ~19.4 MB used
  float* dinv  = (float*)(ws + 0);          // [8][4096]          131,072 B
  float* part  = (float*)(ws + 131072);     // [8][8][64][64]   1,048,576 B
  float* attn2 = (float*)(ws + 1179648);    // [8][64][64]        131,072 B
  float* spre  = (float*)(ws + 1310720);    // [8][64][4096]    8,388,608 B
  float* cpre  = (float*)(ws + 9699328);    // [8][64][4096]    8,388,608 B
  float* Wqk   = (float*)(ws + 18087936);   // [256][1024]      1,048,576 B
  float* bqk   = (float*)(ws + 19136512);   // [256]                1,024 B
  float* Wf    = (float*)(ws + 19137536);   // [512][128]         262,144 B
  float* bfb   = (float*)(ws + 19399680);   // [512]                2,048 B

  k_combine_qk<<<256, 256, 0, stream>>>(wt, bt, wb, bb, s_w1, s_b1, s_w2, s_b2,
                                        c_wq, c_bq, c_wk, c_bk, Wqk, bqk);
  k_combine_f<<<512, 128, 0, stream>>>(f_w, f_b, s_wo, s_bo, c_wo, c_bo, Wf, bfb);
  k_gemm_qk<<<dim3(32, 4, 8), 256, 0, stream>>>(top, bot, Wqk, bqk, qk);
  k_sp_stats<<<dim3(64, 8), 256, 0, stream>>>(qk, dinv);
  k_ch_scores<<<dim3(8, 8), 256, 0, stream>>>(qk, part);
  k_ch_softmax<<<8, 64, 0, stream>>>(part, attn2);
  k_ch_apply<<<dim3(16, 8), 256, 0, stream>>>(qk, attn2, cpre);
  k_sp_apply<<<dim3(64, 8), 256, 0, stream>>>(qk, dinv, spre);
  k_final<<<dim3(32, 8, 8), 256, 0, stream>>>(spre, cpre, Wf, bfb, out);
}

// Round 3
// 924.905 us; speedup vs baseline: 1.7234x; 1.7234x over previous
//
#include <hip/hip_runtime.h>

typedef unsigned short u16;
typedef unsigned int   u32;
typedef __attribute__((ext_vector_type(8))) short short8;  // 8 bf16 = one MFMA A/B frag
typedef __attribute__((ext_vector_type(4))) float f32x4;   // MFMA C/D frag

__device__ __forceinline__ u16 f2bf(float f) {
  u32 u = __float_as_uint(f);
  u32 r = u + 0x7fffu + ((u >> 16) & 1u);
  return (u16)(r >> 16);
}

// ---------------------------------------------------------------------------
// Kernel 1: fold q/k projections into the input convs. (unchanged)
// ---------------------------------------------------------------------------
__global__ __launch_bounds__(256) void k_combine_qk(
    const float* __restrict__ wt, const float* __restrict__ bt,
    const float* __restrict__ wb, const float* __restrict__ bb,
    const float* __restrict__ s_w1, const float* __restrict__ s_b1,
    const float* __restrict__ s_w2, const float* __restrict__ s_b2,
    const float* __restrict__ c_wq, const float* __restrict__ c_bq,
    const float* __restrict__ c_wk, const float* __restrict__ c_bk,
    float* __restrict__ Wqk, float* __restrict__ bqk) {
  int j = blockIdx.x;            // 0..255
  int g = j >> 6, r = j & 63;
  const float* sw; const float* sb;
  if (g == 0)      { sw = s_w1; sb = s_b1; }
  else if (g == 1) { sw = s_w2; sb = s_b2; }
  else if (g == 2) { sw = c_wq; sb = c_bq; }
  else             { sw = c_wk; sb = c_bk; }
  int cbase = (g < 2) ? 0 : 256;

  __shared__ float swr[256];
  __shared__ float red[256];
  int t = threadIdx.x;
  swr[t] = sw[r * 256 + t];
  __syncthreads();

  float a0 = 0.f, a1 = 0.f, a2 = 0.f, a3 = 0.f;
  for (int c = 0; c < 256; ++c) {
    float a = swr[c];
    int row = (cbase + c) * 512;
    a0 += a * wt[row + t];
    a1 += a * wt[row + 256 + t];
    a2 += a * wb[row + t];
    a3 += a * wb[row + 256 + t];
  }
  Wqk[j * 1024 + t]       = a0;
  Wqk[j * 1024 + 256 + t] = a1;
  Wqk[j * 1024 + 512 + t] = a2;
  Wqk[j * 1024 + 768 + t] = a3;

  red[t] = swr[t] * (bt[cbase + t] + bb[cbase + t]);
  __syncthreads();
  for (int s = 128; s > 0; s >>= 1) {
    if (t < s) red[t] += red[t + s];
    __syncthreads();
  }
  if (t == 0) bqk[j] = red[0] + sb[r];
}

// ---------------------------------------------------------------------------
// Kernel 2: fold s_wo / c_wo into the final conv. (unchanged)
// ---------------------------------------------------------------------------
__global__ __launch_bounds__(128) void k_combine_f(
    const float* __restrict__ f_w, const float* __restrict__ f_b,
    const float* __restrict__ s_wo, const float* __restrict__ s_bo,
    const float* __restrict__ c_wo, const float* __restrict__ c_bo,
    float* __restrict__ Wf, float* __restrict__ bfb) {
  int o = blockIdx.x;   // 0..511
  int t = threadIdx.x;  // 0..127
  __shared__ float fwr[512];
  __shared__ float red[128];
  for (int i = t; i < 512; i += 128) fwr[i] = f_w[o * 512 + i];
  __syncthreads();

  float acc = 0.f;
  if (t < 64) {
    for (int c = 0; c < 256; ++c) acc += fwr[c] * s_wo[c * 64 + t];
  } else {
    int rr = t - 64;
    for (int c = 0; c < 256; ++c) acc += fwr[256 + c] * c_wo[c * 64 + rr];
  }
  Wf[o * 128 + t] = acc;

  red[t] = fwr[t] * s_bo[t] + fwr[t + 128] * s_bo[t + 128]
         + fwr[256 + t] * c_bo[t] + fwr[384 + t] * c_bo[t + 128];
  __syncthreads();
  for (int s = 64; s > 0; s >>= 1) {
    if (t < s) red[t] += red[t + s];
    __syncthreads();
  }
  if (t == 0) bfb[o] = red[0] + f_b[o];
}

// ---------------------------------------------------------------------------
// Kernel 3: qk[b][j][n] = sum_k Wqk[j][k] * {top|bottom}[b][k][n] + bqk[j]
// (unchanged fp32 this round — next MFMA target)
// ---------------------------------------------------------------------------
__global__ __launch_bounds__(256) void k_gemm_qk(
    const float* __restrict__ top, const float* __restrict__ bot,
    const float* __restrict__ Wqk, const float* __restrict__ bqk,
    float* __restrict__ qk) {
  int b = blockIdx.z, j0 = blockIdx.y * 64, n0 = blockIdx.x * 128;
  __shared__ float As[32][64];
  __shared__ float Xs[32][128];
  int t = threadIdx.x;
  int jg = t >> 5, nt = t & 31;
  float acc[8][4];
#pragma unroll
  for (int q = 0; q < 8; ++q)
#pragma unroll
    for (int p = 0; p < 4; ++p) acc[q][p] = 0.f;

  for (int kc = 0; kc < 1024; kc += 32) {
    __syncthreads();
#pragma unroll
    for (int i = t; i < 2048; i += 256) {
      int jl = i >> 5, kk = i & 31;
      As[kk][jl] = Wqk[(j0 + jl) * 1024 + kc + kk];
    }
    const float* src = (kc < 512) ? top : bot;
    int c0 = (kc < 512) ? kc : kc - 512;
#pragma unroll
    for (int i = t; i < 1024; i += 256) {
      int kk = i >> 5, w = i & 31;
      float4 v = *reinterpret_cast<const float4*>(
          src + (size_t)(b * 512 + c0 + kk) * 4096 + n0 + w * 4);
      *reinterpret_cast<float4*>(&Xs[kk][w * 4]) = v;
    }
    __syncthreads();
#pragma unroll
    for (int kk = 0; kk < 32; ++kk) {
      float4 a0 = *reinterpret_cast<const float4*>(&As[kk][jg * 8]);
      float4 a1 = *reinterpret_cast<const float4*>(&As[kk][jg * 8 + 4]);
      float4 bx = *reinterpret_cast<const float4*>(&Xs[kk][nt * 4]);
      float av[8] = {a0.x, a0.y, a0.z, a0.w, a1.x, a1.y, a1.z, a1.w};
      float bv[4] = {bx.x, bx.y, bx.z, bx.w};
#pragma unroll
      for (int q = 0; q < 8; ++q)
#pragma unroll
        for (int p = 0; p < 4; ++p) acc[q][p] += av[q] * bv[p];
    }
  }
#pragma unroll
  for (int q = 0; q < 8; ++q) {
    int j = j0 + jg * 8 + q;
    float bias = bqk[j];
    float4 v = make_float4(acc[q][0] + bias, acc[q][1] + bias,
                           acc[q][2] + bias, acc[q][3] + bias);
    *reinterpret_cast<float4*>(&qk[(size_t)(b * 256 + j) * 4096 + n0 + nt * 4]) = v;
  }
}

// ---------------------------------------------------------------------------
// Kernel T1: build channel-minor bf16 copies of q1,k1 for MFMA fragments.
// q1t[b][n][r] = bf16(qk[b][r][n])       (j 0..63)
// k1t[b][m][r] = bf16(qk[b][64+r][m])    (j 64..127)
// ---------------------------------------------------------------------------
__global__ __launch_bounds__(256) void k_transpose_qk(
    const float* __restrict__ qk, u16* __restrict__ q1t, u16* __restrict__ k1t) {
  int b = blockIdx.y, n0 = blockIdx.x * 64;
  __shared__ u16 T[128][68];
  int t = threadIdx.x;
  for (int i = t; i < 8192; i += 256) {
    int j = i >> 6, n = i & 63;
    T[j][n] = f2bf(qk[((size_t)(b * 256) + j) * 4096 + n0 + n]);
  }
  __syncthreads();
  int n = t & 63, h = t >> 6;           // h=0,1 -> q1t halves; h=2,3 -> k1t halves
  u16 buf[32];
#pragma unroll
  for (int jj = 0; jj < 32; ++jj) buf[jj] = T[h * 32 + jj][n];
  u16* dst;
  if (h < 2) dst = q1t + ((size_t)(b * 4096) + n0 + n) * 64 + h * 32;
  else       dst = k1t + ((size_t)(b * 4096) + n0 + n) * 64 + (h - 2) * 32;
  u32* d32 = reinterpret_cast<u32*>(dst);
#pragma unroll
  for (int k = 0; k < 16; ++k)
    d32[k] = (u32)buf[2 * k] | ((u32)buf[2 * k + 1] << 16);
}

// ---------------------------------------------------------------------------
// Kernel 4 (MFMA): spatial softmax denominators.
// S[n,m] = sum_r q1[r,n]k1[r,m]; dinv[b,n] = 1/sum_m exp(S[n,m])
// Block: (n-tile 64, b). Wave wv handles m-tiles wv, wv+4, ...
// A frag: Qs[n][r] rows; B frag: k1t[m][r] rows from global (L2-resident).
// ---------------------------------------------------------------------------
__global__ __launch_bounds__(256) void k_sp_stats_mfma(
    const u16* __restrict__ q1t, const u16* __restrict__ k1t,
    float* __restrict__ dinv) {
  int b = blockIdx.y, n0 = blockIdx.x * 64;
  __shared__ u16 Qs[64][72];
  __shared__ float red[4][64][16];
  int t = threadIdx.x;
  int wv = t >> 6, lane = t & 63;
  int q = lane >> 4, l = lane & 15;

  {
    const u32* src = reinterpret_cast<const u32*>(q1t + ((size_t)(b * 4096) + n0) * 64);
    for (int i = t; i < 2048; i += 256) {
      int n = i >> 5, c = i & 31;
      reinterpret_cast<u32*>(&Qs[n][0])[c] = src[n * 32 + c];
    }
  }
  __syncthreads();

  short8 afr[4][2];
#pragma unroll
  for (int tn = 0; tn < 4; ++tn)
#pragma unroll
    for (int kh = 0; kh < 2; ++kh)
      afr[tn][kh] = *reinterpret_cast<const short8*>(&Qs[tn * 16 + l][kh * 32 + q * 8]);

  const u16* kbase = k1t + (size_t)b * 4096 * 64;
  float dsum[4][4];
#pragma unroll
  for (int tn = 0; tn < 4; ++tn)
#pragma unroll
    for (int i = 0; i < 4; ++i) dsum[tn][i] = 0.f;

  for (int mt = wv; mt < 64; mt += 4) {
    int m0 = mt * 64;
#pragma unroll
    for (int tm = 0; tm < 4; ++tm) {
      const u16* kp = kbase + ((size_t)(m0 + tm * 16 + l)) * 64;
      short8 b0 = *reinterpret_cast<const short8*>(kp + q * 8);
      short8 b1 = *reinterpret_cast<const short8*>(kp + 32 + q * 8);
#pragma unroll
      for (int tn = 0; tn < 4; ++tn) {
        f32x4 acc = {0.f, 0.f, 0.f, 0.f};
        acc = __builtin_amdgcn_mfma_f32_16x16x32_bf16(afr[tn][0], b0, acc, 0, 0, 0);
        acc = __builtin_amdgcn_mfma_f32_16x16x32_bf16(afr[tn][1], b1, acc, 0, 0, 0);
#pragma unroll
        for (int i = 0; i < 4; ++i) dsum[tn][i] += __expf(acc[i]);
      }
    }
  }

#pragma unroll
  for (int tn = 0; tn < 4; ++tn)
#pragma unroll
    for (int i = 0; i < 4; ++i)
      red[wv][tn * 16 + q * 4 + i][l] = dsum[tn][i];
  __syncthreads();
  if (t < 64) {
    float s = 0.f;
#pragma unroll
    for (int v = 0; v < 4; ++v)
#pragma unroll
      for (int u = 0; u < 16; ++u) s += red[v][t][u];
    dinv[(size_t)b * 4096 + n0 + t] = 1.0f / s;
  }
}

// ---------------------------------------------------------------------------
// Kernel T2: k1d[b][r][n] = bf16(k1[r][n] * dinv[n])  — dinv folded into V.
// ---------------------------------------------------------------------------
__global__ __launch_bounds__(256) void k_scale_k1d(
    const float* __restrict__ qk, const float* __restrict__ dinv,
    u16* __restrict__ k1d) {
  int b = blockIdx.x >> 6, r = blockIdx.x & 63;
  const float* src = qk + ((size_t)(b * 256) + 64 + r) * 4096;
  const float* dv = dinv + (size_t)b * 4096;
  u16* dst = k1d + ((size_t)(b * 64) + r) * 4096;
  for (int i = threadIdx.x; i < 4096; i += 256)
    dst[i] = f2bf(src[i] * dv[i]);
}

// ---------------------------------------------------------------------------
// Kernel 8 (MFMA): spatial apply.
// spre[b][r][m] = sum_n k1d[r,n] * exp(S[n,m]),  S recomputed via MFMA.
// Block: (m-tile 64, b); wave wv owns m-cols wv*16..wv*16+15 (W round-trip
// through LDS is wave-private -> no extra barrier).
// ---------------------------------------------------------------------------
__global__ __launch_bounds__(256) void k_sp_apply_mfma(
    const u16* __restrict__ q1t, const u16* __restrict__ k1t,
    const u16* __restrict__ k1d, float* __restrict__ spre) {
  int b = blockIdx.y, m0 = blockIdx.x * 64;
  __shared__ u16 Kt[64][72];   // k1t m-tile: [m_local][r]
  __shared__ u16 Qs[64][72];   // q1t n-tile: [n_local][r]
  __shared__ u16 Ks[64][72];   // k1d n-tile: [r][n_local]
  __shared__ u16 Wt[64][72];   // exp(S):     [m_local][n_local]
  int t = threadIdx.x;
  int wv = t >> 6, lane = t & 63;
  int q = lane >> 4, l = lane & 15;

  {
    const u32* src = reinterpret_cast<const u32*>(k1t + ((size_t)(b * 4096) + m0) * 64);
    for (int i = t; i < 2048; i += 256) {
      int m = i >> 5, c = i & 31;
      reinterpret_cast<u32*>(&Kt[m][0])[c] = src[m * 32 + c];
    }
  }
  __syncthreads();

  // B frags for S: this wave's 16 m-columns, K=64 in two halves.
  short8 bS0 = *reinterpret_cast<const short8*>(&Kt[wv * 16 + l][q * 8]);
  short8 bS1 = *reinterpret_cast<const short8*>(&Kt[wv * 16 + l][32 + q * 8]);

  f32x4 accO[4];
#pragma unroll
  for (int tr = 0; tr < 4; ++tr) accO[tr] = (f32x4){0.f, 0.f, 0.f, 0.f};

  const u32* qsrc_base = reinterpret_cast<const u32*>(q1t + (size_t)(b * 4096) * 64);
  const u32* ksrc_base = reinterpret_cast<const u32*>(k1d + (size_t)(b * 64) * 4096);

  for (int ntile = 0; ntile < 64; ++ntile) {
    int n0 = ntile * 64;
    __syncthreads();
    // stage q1t n-tile: rows n_local, 32 u32 each
    for (int i = t; i < 2048; i += 256) {
      int n = i >> 5, c = i & 31;
      reinterpret_cast<u32*>(&Qs[n][0])[c] = qsrc_base[(size_t)(n0 + n) * 32 + c];
    }
    // stage k1d n-tile: rows r, cols n_local (natural layout slice)
    for (int i = t; i < 2048; i += 256) {
      int r = i >> 5, c = i & 31;
      reinterpret_cast<u32*>(&Ks[r][0])[c] = ksrc_base[(size_t)r * 2048 + (n0 >> 1) + c];
    }
    __syncthreads();

    // Phase 1: S[n,m] for this wave's 16 m-cols; write exp(S) to Wt rows.
#pragma unroll
    for (int tn = 0; tn < 4; ++tn) {
      short8 a0 = *reinterpret_cast<const short8*>(&Qs[tn * 16 + l][q * 8]);
      short8 a1 = *reinterpret_cast<const short8*>(&Qs[tn * 16 + l][32 + q * 8]);
      f32x4 s = {0.f, 0.f, 0.f, 0.f};
      s = __builtin_amdgcn_mfma_f32_16x16x32_bf16(a0, bS0, s, 0, 0, 0);
      s = __builtin_amdgcn_mfma_f32_16x16x32_bf16(a1, bS1, s, 0, 0, 0);
      u16 w0 = f2bf(__expf(s[0]));
      u16 w1 = f2bf(__expf(s[1]));
      u16 w2 = f2bf(__expf(s[2]));
      u16 w3 = f2bf(__expf(s[3]));
      uint2 pk;
      pk.x = (u32)w0 | ((u32)w1 << 16);
      pk.y = (u32)w2 | ((u32)w3 << 16);
      *reinterpret_cast<uint2*>(&Wt[wv * 16 + l][tn * 16 + q * 4]) = pk;
    }

    // Phase 2: O[r, m] += k1d[r, n] * W[n, m]  (Wt rows are wave-private)
    short8 bW0 = *reinterpret_cast<const short8*>(&Wt[wv * 16 + l][q * 8]);
    short8 bW1 = *reinterpret_cast<const short8*>(&Wt[wv * 16 + l][32 + q * 8]);
#pragma unroll
    for (int tr = 0; tr < 4; ++tr) {
      short8 a0 = *reinterpret_cast<const short8*>(&Ks[tr * 16 + l][q * 8]);
      short8 a1 = *reinterpret_cast<const short8*>(&Ks[tr * 16 + l][32 + q * 8]);
      accO[tr] = __builtin_amdgcn_mfma_f32_16x16x32_bf16(a0, bW0, accO[tr], 0, 0, 0);
      accO[tr] = __builtin_amdgcn_mfma_f32_16x16x32_bf16(a1, bW1, accO[tr], 0, 0, 0);
    }
  }

#pragma unroll
  for (int tr = 0; tr < 4; ++tr)
#pragma unroll
    for (int i = 0; i < 4; ++i)
      spre[(size_t)(b * 64 + tr * 16 + q * 4 + i) * 4096 + m0 + wv * 16 + l] = accO[tr][i];
}

// ---------------------------------------------------------------------------
// Kernel 5: channel attention partial scores. (unchanged)
// ---------------------------------------------------------------------------
__global__ __launch_bounds__(256) void k_ch_scores(
    const float* __restrict__ qk, float* __restrict__ part) {
  int b = blockIdx.y, ch = blockIdx.x;
  const float* q2 = qk + (size_t)(b * 256 + 128) * 4096;
  const float* k2 = qk + (size_t)(b * 256 + 192) * 4096;
  __shared__ float Qs[64][65];
  __shared__ float Ks[64][65];
  int t = threadIdx.x, ti = t >> 4, tj = t & 15;
  float acc[4][4] = {};

  for (int sub = 0; sub < 8; ++sub) {
    int n0 = ch * 512 + sub * 64;
    __syncthreads();
    for (int i = t; i < 4096; i += 256) {
      int r = i >> 6, n = i & 63;
      Qs[r][n] = q2[(size_t)r * 4096 + n0 + n];
      Ks[r][n] = k2[(size_t)r * 4096 + n0 + n];
    }
    __syncthreads();
#pragma unroll
    for (int n = 0; n < 64; ++n) {
      float qa[4], ka[4];
#pragma unroll
      for (int i = 0; i < 4; ++i) qa[i] = Qs[ti * 4 + i][n];
#pragma unroll
      for (int jx = 0; jx < 4; ++jx) ka[jx] = Ks[tj * 4 + jx][n];
#pragma unroll
      for (int i = 0; i < 4; ++i)
#pragma unroll
        for (int jx = 0; jx < 4; ++jx) acc[i][jx] += qa[i] * ka[jx];
    }
  }
#pragma unroll
  for (int i = 0; i < 4; ++i)
#pragma unroll
    for (int jx = 0; jx < 4; ++jx)
      part[(size_t)(b * 8 + ch) * 4096 + (ti * 4 + i) * 64 + tj * 4 + jx] = acc[i][jx];
}

// ---------------------------------------------------------------------------
// Kernel 6: reduce partials + row softmax -> attn2[b][r][s] (unchanged)
// ---------------------------------------------------------------------------
__global__ __launch_bounds__(64) void k_ch_softmax(
    const float* __restrict__ part, float* __restrict__ attn2) {
  int b = blockIdx.x, r = threadIdx.x;
  float v[64];
  float mx = -1e30f;
#pragma unroll
  for (int s = 0; s < 64; ++s) {
    float sum = 0.f;
#pragma unroll
    for (int c = 0; c < 8; ++c)
      sum += part[(size_t)(b * 8 + c) * 4096 + r * 64 + s];
    v[s] = sum;
    mx = fmaxf(mx, sum);
  }
  float den = 0.f;
#pragma unroll
  for (int s = 0; s < 64; ++s) { v[s] = __expf(v[s] - mx); den += v[s]; }
  float inv = 1.0f / den;
#pragma unroll
  for (int s = 0; s < 64; ++s)
    attn2[(size_t)b * 4096 + r * 64 + s] = v[s] * inv;
}

// ---------------------------------------------------------------------------
// Kernel 7: cpre[b][r][n] = sum_s attn2[r,s] * k2[s,n] (unchanged)
// ---------------------------------------------------------------------------
__global__ __launch_bounds__(256) void k_ch_apply(
    const float* __restrict__ qk, const float* __restrict__ attn2,
    float* __restrict__ cpre) {
  int b = blockIdx.y;
  int n = blockIdx.x * 256 + threadIdx.x;
  const float* k2 = qk + (size_t)(b * 256 + 192) * 4096;
  __shared__ float As[64][64];
  int t = threadIdx.x;
  for (int i = t; i < 4096; i += 256) As[i >> 6][i & 63] = attn2[(size_t)b * 4096 + i];
  __syncthreads();

  float acc[64];
#pragma unroll
  for (int r = 0; r < 64; ++r) acc[r] = 0.f;
  for (int s4 = 0; s4 < 64; s4 += 4) {
    float kv0 = k2[(size_t)(s4 + 0) * 4096 + n];
    float kv1 = k2[(size_t)(s4 + 1) * 4096 + n];
    float kv2 = k2[(size_t)(s4 + 2) * 4096 + n];
    float kv3 = k2[(size_t)(s4 + 3) * 4096 + n];
#pragma unroll
    for (int r = 0; r < 64; ++r) {
      float4 w = *reinterpret_cast<const float4*>(&As[r][s4]);
      acc[r] += w.x * kv0 + w.y * kv1 + w.z * kv2 + w.w * kv3;
    }
  }
#pragma unroll
  for (int r = 0; r < 64; ++r)
    cpre[(size_t)(b * 64 + r) * 4096 + n] = acc[r];
}

// ---------------------------------------------------------------------------
// Kernel 9: final fused conv. (unchanged)
// ---------------------------------------------------------------------------
__global__ __launch_bounds__(256) void k_final(
    const float* __restrict__ spre, const float* __restrict__ cpre,
    const float* __restrict__ Wf, const float* __restrict__ bfb,
    float* __restrict__ out) {
  int b = blockIdx.z, o0 = blockIdx.y * 64, n0 = blockIdx.x * 128;
  __shared__ float As[32][64];
  __shared__ float Xs[32][128];
  int t = threadIdx.x, og = t >> 5, nt = t & 31;
  float acc[8][4];
#pragma unroll
  for (int q = 0; q < 8; ++q)
#pragma unroll
    for (int p = 0; p < 4; ++p) acc[q][p] = 0.f;

  for (int kc = 0; kc < 128; kc += 32) {
    __syncthreads();
#pragma unroll
    for (int i = t; i < 2048; i += 256) {
      int ol = i >> 5, kk = i & 31;
      As[kk][ol] = Wf[(o0 + ol) * 128 + kc + kk];
    }
    const float* src = (kc < 64) ? spre : cpre;
    int r0 = (kc < 64) ? kc : kc - 64;
#pragma unroll
    for (int i = t; i < 1024; i += 256) {
      int kk = i >> 5, w = i & 31;
      float4 v = *reinterpret_cast<const float4*>(
          src + (size_t)(b * 64 + r0 + kk) * 4096 + n0 + w * 4);
      *reinterpret_cast<float4*>(&Xs[kk][w * 4]) = v;
    }
    __syncthreads();
#pragma unroll
    for (int kk = 0; kk < 32; ++kk) {
      float4 a0 = *reinterpret_cast<const float4*>(&As[kk][og * 8]);
      float4 a1 = *reinterpret_cast<const float4*>(&As[kk][og * 8 + 4]);
      float4 bx = *reinterpret_cast<const float4*>(&Xs[kk][nt * 4]);
      float av[8] = {a0.x, a0.y, a0.z, a0.w, a1.x, a1.y, a1.z, a1.w};
      float bv[4] = {bx.x, bx.y, bx.z, bx.w};
#pragma unroll
      for (int q = 0; q < 8; ++q)
#pragma unroll
        for (int p = 0; p < 4; ++p) acc[q][p] += av[q] * bv[p];
    }
  }
#pragma unroll
  for (int q = 0; q < 8; ++q) {
    int o = o0 + og * 8 + q;
    float bias = bfb[o];
    float4 v = make_float4(acc[q][0] + bias, acc[q][1] + bias,
                           acc[q][2] + bias, acc[q][3] + bias);
    *reinterpret_cast<float4*>(&out[(size_t)(b * 512 + o) * 4096 + n0 + nt * 4]) = v;
  }
}

// ---------------------------------------------------------------------------
extern "C" void kernel_launch(void* const* d_in, const int* in_sizes, int n_in,
                              void* d_out, int out_size, void* d_ws, size_t ws_size,
                              hipStream_t stream) {
  const float* top  = (const float*)d_in[0];
  const float* bot  = (const float*)d_in[1];
  const float* wt   = (const float*)d_in[2];
  const float* bt   = (const float*)d_in[3];
  const float* wb   = (const float*)d_in[4];
  const float* bb   = (const float*)d_in[5];
  const float* s_w1 = (const float*)d_in[6];
  const float* s_b1 = (const float*)d_in[7];
  const float* s_w2 = (const float*)d_in[8];
  const float* s_b2 = (const float*)d_in[9];
  const float* s_wo = (const float*)d_in[10];
  const float* s_bo = (const float*)d_in[11];
  const float* c_wq = (const float*)d_in[12];
  const float* c_bq = (const float*)d_in[13];
  const float* c_wk = (const float*)d_in[14];
  const float* c_bk = (const float*)d_in[15];
  const float* c_wo = (const float*)d_in[16];
  const float* c_bo = (const float*)d_in[17];
  const float* f_w  = (const float*)d_in[18];
  const float* f_b  = (const float*)d_in[19];
  float* out = (float*)d_out;

  // d_out (64 MB) doubles as scratch until k_final overwrites it:
  //   [0,32MB)  qk fp32 [8][256][4096]
  //   [32,36MB) q1t bf16 [8][4096][64]
  //   [36,40MB) k1t bf16 [8][4096][64]
  //   [40,44MB) k1d bf16 [8][64][4096]
  char* ob = (char*)d_out;
  float* qk = (float*)ob;
  u16* q1t = (u16*)(ob + 33554432);
  u16* k1t = (u16*)(ob + 37748736);
  u16* k1d = (u16*)(ob + 41943040);

  char* ws = (char*)d_ws;   // ~19.4 MB used
  float* dinv  = (float*)(ws + 0);          // [8][4096]          131,072 B
  float* part  = (float*)(ws + 131072);     // [8][8][64][64]   1,048,576 B
  float* attn2 = (float*)(ws + 1179648);    // [8][64][64]        131,072 B
  float* spre  = (float*)(ws + 1310720);    // [8][64][4096]    8,388,608 B
  float* cpre  = (float*)(ws + 9699328);    // [8][64][4096]    8,388,608 B
  float* Wqk   = (float*)(ws + 18087936);   // [256][1024]      1,048,576 B
  float* bqk   = (float*)(ws + 19136512);   // [256]                1,024 B
  float* Wf    = (float*)(ws + 19137536);   // [512][128]         262,144 B
  float* bfb   = (float*)(ws + 19399680);   // [512]                2,048 B

  k_combine_qk<<<256, 256, 0, stream>>>(wt, bt, wb, bb, s_w1, s_b1, s_w2, s_b2,
                                        c_wq, c_bq, c_wk, c_bk, Wqk, bqk);
  k_combine_f<<<512, 128, 0, stream>>>(f_w, f_b, s_wo, s_bo, c_wo, c_bo, Wf, bfb);
  k_gemm_qk<<<dim3(32, 4, 8), 256, 0, stream>>>(top, bot, Wqk, bqk, qk);
  k_transpose_qk<<<dim3(64, 8), 256, 0, stream>>>(qk, q1t, k1t);
  k_sp_stats_mfma<<<dim3(64, 8), 256, 0, stream>>>(q1t, k1t, dinv);
  k_ch_scores<<<dim3(8, 8), 256, 0, stream>>>(qk, part);
  k_ch_softmax<<<8, 64, 0, stream>>>(part, attn2);
  k_ch_apply<<<dim3(16, 8), 256, 0, stream>>>(qk, attn2, cpre);
  k_scale_k1d<<<512, 256, 0, stream>>>(qk, dinv, k1d);
  k_sp_apply_mfma<<<dim3(64, 8), 256, 0, stream>>>(q1t, k1t, k1d, spre);
  k_final<<<dim3(32, 8, 8), 256, 0, stream>>>(spre, cpre, Wf, bfb, out);
}

// Round 4
// 593.414 us; speedup vs baseline: 2.6862x; 1.5586x over previous
//
#include <hip/hip_runtime.h>

typedef unsigned short u16;
typedef unsigned int   u32;
typedef __attribute__((ext_vector_type(8))) short short8;  // 8 bf16 = one MFMA A/B frag
typedef __attribute__((ext_vector_type(4))) float f32x4;   // MFMA C/D frag

__device__ __forceinline__ u16 f2bf(float f) {
  u32 u = __float_as_uint(f);
  u32 r = u + 0x7fffu + ((u >> 16) & 1u);
  return (u16)(r >> 16);
}

// ---------------------------------------------------------------------------
// Kernel 1: fold q/k projections into the input convs; emit bf16 Wqkb.
// Wqkb[j][0:512]   = bf16( sw_g[r,:] @ wt[rows cbase..cbase+255][:] )
// Wqkb[j][512:1024]= bf16( sw_g[r,:] @ wb[...] )
// bqk[j] = sw_g[r,:] @ (bt+bb)[cbase:...] + sb_g[r]
// ---------------------------------------------------------------------------
__global__ __launch_bounds__(256) void k_combine_qk(
    const float* __restrict__ wt, const float* __restrict__ bt,
    const float* __restrict__ wb, const float* __restrict__ bb,
    const float* __restrict__ s_w1, const float* __restrict__ s_b1,
    const float* __restrict__ s_w2, const float* __restrict__ s_b2,
    const float* __restrict__ c_wq, const float* __restrict__ c_bq,
    const float* __restrict__ c_wk, const float* __restrict__ c_bk,
    u16* __restrict__ Wqkb, float* __restrict__ bqk) {
  int j = blockIdx.x;            // 0..255
  int g = j >> 6, r = j & 63;
  const float* sw; const float* sb;
  if (g == 0)      { sw = s_w1; sb = s_b1; }
  else if (g == 1) { sw = s_w2; sb = s_b2; }
  else if (g == 2) { sw = c_wq; sb = c_bq; }
  else             { sw = c_wk; sb = c_bk; }
  int cbase = (g < 2) ? 0 : 256;

  __shared__ float swr[256];
  __shared__ float red[256];
  int t = threadIdx.x;
  swr[t] = sw[r * 256 + t];
  __syncthreads();

  float a0 = 0.f, a1 = 0.f, a2 = 0.f, a3 = 0.f;
  for (int c = 0; c < 256; ++c) {
    float a = swr[c];
    int row = (cbase + c) * 512;
    a0 += a * wt[row + t];
    a1 += a * wt[row + 256 + t];
    a2 += a * wb[row + t];
    a3 += a * wb[row + 256 + t];
  }
  Wqkb[j * 1024 + t]       = f2bf(a0);
  Wqkb[j * 1024 + 256 + t] = f2bf(a1);
  Wqkb[j * 1024 + 512 + t] = f2bf(a2);
  Wqkb[j * 1024 + 768 + t] = f2bf(a3);

  red[t] = swr[t] * (bt[cbase + t] + bb[cbase + t]);
  __syncthreads();
  for (int s = 128; s > 0; s >>= 1) {
    if (t < s) red[t] += red[t + s];
    __syncthreads();
  }
  if (t == 0) bqk[j] = red[0] + sb[r];
}

// ---------------------------------------------------------------------------
// Kernel 2: fold s_wo / c_wo into the final conv; emit bf16 Wfb.
// ---------------------------------------------------------------------------
__global__ __launch_bounds__(128) void k_combine_f(
    const float* __restrict__ f_w, const float* __restrict__ f_b,
    const float* __restrict__ s_wo, const float* __restrict__ s_bo,
    const float* __restrict__ c_wo, const float* __restrict__ c_bo,
    u16* __restrict__ Wfb, float* __restrict__ bfb) {
  int o = blockIdx.x;   // 0..511
  int t = threadIdx.x;  // 0..127
  __shared__ float fwr[512];
  __shared__ float red[128];
  for (int i = t; i < 512; i += 128) fwr[i] = f_w[o * 512 + i];
  __syncthreads();

  float acc = 0.f;
  if (t < 64) {
    for (int c = 0; c < 256; ++c) acc += fwr[c] * s_wo[c * 64 + t];
  } else {
    int rr = t - 64;
    for (int c = 0; c < 256; ++c) acc += fwr[256 + c] * c_wo[c * 64 + rr];
  }
  Wfb[o * 128 + t] = f2bf(acc);

  red[t] = fwr[t] * s_bo[t] + fwr[t + 128] * s_bo[t + 128]
         + fwr[256 + t] * c_bo[t] + fwr[384 + t] * c_bo[t + 128];
  __syncthreads();
  for (int s = 64; s > 0; s >>= 1) {
    if (t < s) red[t] += red[t + s];
    __syncthreads();
  }
  if (t == 0) bfb[o] = red[0] + f_b[o];
}

// ---------------------------------------------------------------------------
// Kernel 3 (MFMA): qk[b][j][n] = sum_k Wqk[j][k]*x[b][k][n] + bqk[j]
// M=256, K=1024 (512 top + 512 bottom), N=4096/batch. 128x128 tile, BK=32.
// A = Wqkb bf16 [j][k] (k-minor, natural). X staged fp32->bf16 with in-LDS
// transpose to [n][k]. 4 waves (2x2), each 64x64 via 4x4 16x16x32 MFMAs.
// ---------------------------------------------------------------------------
__global__ __launch_bounds__(256) void k_gemm_qk_mfma(
    const float* __restrict__ top, const float* __restrict__ bot,
    const u16* __restrict__ Wqkb, const float* __restrict__ bqk,
    float* __restrict__ qk) {
  int b = blockIdx.z, j0 = blockIdx.y * 128, n0 = blockIdx.x * 128;
  __shared__ u16 Aj[128][40];   // [j_local][k] pad->80B rows (16B aligned)
  __shared__ u16 Xs[128][40];   // [n_local][k]
  int t = threadIdx.x;
  int wv = t >> 6, lane = t & 63;
  int wr = wv >> 1, wc = wv & 1;
  int q = lane >> 4, l = lane & 15;

  f32x4 acc[4][4];
#pragma unroll
  for (int tr = 0; tr < 4; ++tr)
#pragma unroll
    for (int tc = 0; tc < 4; ++tc) acc[tr][tc] = (f32x4){0.f, 0.f, 0.f, 0.f};

  int xn = t & 31;        // n base lane
  int xs = t >> 5;        // slot 0..7

  for (int kc = 0; kc < 1024; kc += 32) {
    __syncthreads();
    {
      const u32* asrc = reinterpret_cast<const u32*>(Wqkb + (size_t)j0 * 1024 + kc);
#pragma unroll
      for (int p = 0; p < 8; ++p) {
        int i = p * 256 + t;
        int row = i >> 4, c = i & 15;
        *reinterpret_cast<u32*>(&Aj[row][c * 2]) = asrc[(size_t)row * 512 + c];
      }
    }
    const float* src = (kc < 512) ? top : bot;
    int c0 = (kc < 512) ? kc : kc - 512;
    const float* xb = src + (size_t)(b * 512 + c0) * 4096 + n0;
#pragma unroll
    for (int p = 0; p < 8; ++p) {
      int n = xn + 32 * (p >> 1);
      int kp = xs + 8 * (p & 1);
      float v0 = xb[(size_t)(2 * kp) * 4096 + n];
      float v1 = xb[(size_t)(2 * kp + 1) * 4096 + n];
      *reinterpret_cast<u32*>(&Xs[n][kp * 2]) =
          (u32)f2bf(v0) | ((u32)f2bf(v1) << 16);
    }
    __syncthreads();

    short8 af[4], bfr[4];
#pragma unroll
    for (int tr = 0; tr < 4; ++tr)
      af[tr] = *reinterpret_cast<const short8*>(&Aj[wr * 64 + tr * 16 + l][q * 8]);
#pragma unroll
    for (int tc = 0; tc < 4; ++tc)
      bfr[tc] = *reinterpret_cast<const short8*>(&Xs[wc * 64 + tc * 16 + l][q * 8]);
#pragma unroll
    for (int tr = 0; tr < 4; ++tr)
#pragma unroll
      for (int tc = 0; tc < 4; ++tc)
        acc[tr][tc] = __builtin_amdgcn_mfma_f32_16x16x32_bf16(
            af[tr], bfr[tc], acc[tr][tc], 0, 0, 0);
  }

#pragma unroll
  for (int tr = 0; tr < 4; ++tr) {
    int j = j0 + wr * 64 + tr * 16 + q * 4;
    float4 bias = *reinterpret_cast<const float4*>(&bqk[j]);
#pragma unroll
    for (int tc = 0; tc < 4; ++tc) {
      int n = n0 + wc * 64 + tc * 16 + l;
      float* dst = qk + (size_t)(b * 256 + j) * 4096 + n;
      dst[0]        = acc[tr][tc][0] + bias.x;
      dst[4096]     = acc[tr][tc][1] + bias.y;
      dst[2 * 4096] = acc[tr][tc][2] + bias.z;
      dst[3 * 4096] = acc[tr][tc][3] + bias.w;
    }
  }
}

// ---------------------------------------------------------------------------
// Kernel T1: build channel-minor bf16 copies of q1,k1 for MFMA fragments.
// ---------------------------------------------------------------------------
__global__ __launch_bounds__(256) void k_transpose_qk(
    const float* __restrict__ qk, u16* __restrict__ q1t, u16* __restrict__ k1t) {
  int b = blockIdx.y, n0 = blockIdx.x * 64;
  __shared__ u16 T[128][68];
  int t = threadIdx.x;
  for (int i = t; i < 8192; i += 256) {
    int j = i >> 6, n = i & 63;
    T[j][n] = f2bf(qk[((size_t)(b * 256) + j) * 4096 + n0 + n]);
  }
  __syncthreads();
  int n = t & 63, h = t >> 6;
  u16 buf[32];
#pragma unroll
  for (int jj = 0; jj < 32; ++jj) buf[jj] = T[h * 32 + jj][n];
  u16* dst;
  if (h < 2) dst = q1t + ((size_t)(b * 4096) + n0 + n) * 64 + h * 32;
  else       dst = k1t + ((size_t)(b * 4096) + n0 + n) * 64 + (h - 2) * 32;
  u32* d32 = reinterpret_cast<u32*>(dst);
#pragma unroll
  for (int k = 0; k < 16; ++k)
    d32[k] = (u32)buf[2 * k] | ((u32)buf[2 * k + 1] << 16);
}

// ---------------------------------------------------------------------------
// Kernel 4 (MFMA): spatial softmax denominators. (unchanged)
// ---------------------------------------------------------------------------
__global__ __launch_bounds__(256) void k_sp_stats_mfma(
    const u16* __restrict__ q1t, const u16* __restrict__ k1t,
    float* __restrict__ dinv) {
  int b = blockIdx.y, n0 = blockIdx.x * 64;
  __shared__ u16 Qs[64][72];
  __shared__ float red[4][64][16];
  int t = threadIdx.x;
  int wv = t >> 6, lane = t & 63;
  int q = lane >> 4, l = lane & 15;

  {
    const u32* src = reinterpret_cast<const u32*>(q1t + ((size_t)(b * 4096) + n0) * 64);
    for (int i = t; i < 2048; i += 256) {
      int n = i >> 5, c = i & 31;
      reinterpret_cast<u32*>(&Qs[n][0])[c] = src[n * 32 + c];
    }
  }
  __syncthreads();

  short8 afr[4][2];
#pragma unroll
  for (int tn = 0; tn < 4; ++tn)
#pragma unroll
    for (int kh = 0; kh < 2; ++kh)
      afr[tn][kh] = *reinterpret_cast<const short8*>(&Qs[tn * 16 + l][kh * 32 + q * 8]);

  const u16* kbase = k1t + (size_t)b * 4096 * 64;
  float dsum[4][4];
#pragma unroll
  for (int tn = 0; tn < 4; ++tn)
#pragma unroll
    for (int i = 0; i < 4; ++i) dsum[tn][i] = 0.f;

  for (int mt = wv; mt < 64; mt += 4) {
    int m0 = mt * 64;
#pragma unroll
    for (int tm = 0; tm < 4; ++tm) {
      const u16* kp = kbase + ((size_t)(m0 + tm * 16 + l)) * 64;
      short8 b0 = *reinterpret_cast<const short8*>(kp + q * 8);
      short8 b1 = *reinterpret_cast<const short8*>(kp + 32 + q * 8);
#pragma unroll
      for (int tn = 0; tn < 4; ++tn) {
        f32x4 acc = {0.f, 0.f, 0.f, 0.f};
        acc = __builtin_amdgcn_mfma_f32_16x16x32_bf16(afr[tn][0], b0, acc, 0, 0, 0);
        acc = __builtin_amdgcn_mfma_f32_16x16x32_bf16(afr[tn][1], b1, acc, 0, 0, 0);
#pragma unroll
        for (int i = 0; i < 4; ++i) dsum[tn][i] += __expf(acc[i]);
      }
    }
  }

#pragma unroll
  for (int tn = 0; tn < 4; ++tn)
#pragma unroll
    for (int i = 0; i < 4; ++i)
      red[wv][tn * 16 + q * 4 + i][l] = dsum[tn][i];
  __syncthreads();
  if (t < 64) {
    float s = 0.f;
#pragma unroll
    for (int v = 0; v < 4; ++v)
#pragma unroll
      for (int u = 0; u < 16; ++u) s += red[v][t][u];
    dinv[(size_t)b * 4096 + n0 + t] = 1.0f / s;
  }
}

// ---------------------------------------------------------------------------
// Kernel T2: k1d[b][r][n] = bf16(k1[r][n] * dinv[n])
// ---------------------------------------------------------------------------
__global__ __launch_bounds__(256) void k_scale_k1d(
    const float* __restrict__ qk, const float* __restrict__ dinv,
    u16* __restrict__ k1d) {
  int b = blockIdx.x >> 6, r = blockIdx.x & 63;
  const float* src = qk + ((size_t)(b * 256) + 64 + r) * 4096;
  const float* dv = dinv + (size_t)b * 4096;
  u16* dst = k1d + ((size_t)(b * 64) + r) * 4096;
  for (int i = threadIdx.x; i < 4096; i += 256)
    dst[i] = f2bf(src[i] * dv[i]);
}

// ---------------------------------------------------------------------------
// Kernel 8 (MFMA): spatial apply. (unchanged)
// ---------------------------------------------------------------------------
__global__ __launch_bounds__(256) void k_sp_apply_mfma(
    const u16* __restrict__ q1t, const u16* __restrict__ k1t,
    const u16* __restrict__ k1d, float* __restrict__ spre) {
  int b = blockIdx.y, m0 = blockIdx.x * 64;
  __shared__ u16 Kt[64][72];
  __shared__ u16 Qs[64][72];
  __shared__ u16 Ks[64][72];
  __shared__ u16 Wt[64][72];
  int t = threadIdx.x;
  int wv = t >> 6, lane = t & 63;
  int q = lane >> 4, l = lane & 15;

  {
    const u32* src = reinterpret_cast<const u32*>(k1t + ((size_t)(b * 4096) + m0) * 64);
    for (int i = t; i < 2048; i += 256) {
      int m = i >> 5, c = i & 31;
      reinterpret_cast<u32*>(&Kt[m][0])[c] = src[m * 32 + c];
    }
  }
  __syncthreads();

  short8 bS0 = *reinterpret_cast<const short8*>(&Kt[wv * 16 + l][q * 8]);
  short8 bS1 = *reinterpret_cast<const short8*>(&Kt[wv * 16 + l][32 + q * 8]);

  f32x4 accO[4];
#pragma unroll
  for (int tr = 0; tr < 4; ++tr) accO[tr] = (f32x4){0.f, 0.f, 0.f, 0.f};

  const u32* qsrc_base = reinterpret_cast<const u32*>(q1t + (size_t)(b * 4096) * 64);
  const u32* ksrc_base = reinterpret_cast<const u32*>(k1d + (size_t)(b * 64) * 4096);

  for (int ntile = 0; ntile < 64; ++ntile) {
    int n0 = ntile * 64;
    __syncthreads();
    for (int i = t; i < 2048; i += 256) {
      int n = i >> 5, c = i & 31;
      reinterpret_cast<u32*>(&Qs[n][0])[c] = qsrc_base[(size_t)(n0 + n) * 32 + c];
    }
    for (int i = t; i < 2048; i += 256) {
      int r = i >> 5, c = i & 31;
      reinterpret_cast<u32*>(&Ks[r][0])[c] = ksrc_base[(size_t)r * 2048 + (n0 >> 1) + c];
    }
    __syncthreads();

#pragma unroll
    for (int tn = 0; tn < 4; ++tn) {
      short8 a0 = *reinterpret_cast<const short8*>(&Qs[tn * 16 + l][q * 8]);
      short8 a1 = *reinterpret_cast<const short8*>(&Qs[tn * 16 + l][32 + q * 8]);
      f32x4 s = {0.f, 0.f, 0.f, 0.f};
      s = __builtin_amdgcn_mfma_f32_16x16x32_bf16(a0, bS0, s, 0, 0, 0);
      s = __builtin_amdgcn_mfma_f32_16x16x32_bf16(a1, bS1, s, 0, 0, 0);
      u16 w0 = f2bf(__expf(s[0]));
      u16 w1 = f2bf(__expf(s[1]));
      u16 w2 = f2bf(__expf(s[2]));
      u16 w3 = f2bf(__expf(s[3]));
      uint2 pk;
      pk.x = (u32)w0 | ((u32)w1 << 16);
      pk.y = (u32)w2 | ((u32)w3 << 16);
      *reinterpret_cast<uint2*>(&Wt[wv * 16 + l][tn * 16 + q * 4]) = pk;
    }

    short8 bW0 = *reinterpret_cast<const short8*>(&Wt[wv * 16 + l][q * 8]);
    short8 bW1 = *reinterpret_cast<const short8*>(&Wt[wv * 16 + l][32 + q * 8]);
#pragma unroll
    for (int tr = 0; tr < 4; ++tr) {
      short8 a0 = *reinterpret_cast<const short8*>(&Ks[tr * 16 + l][q * 8]);
      short8 a1 = *reinterpret_cast<const short8*>(&Ks[tr * 16 + l][32 + q * 8]);
      accO[tr] = __builtin_amdgcn_mfma_f32_16x16x32_bf16(a0, bW0, accO[tr], 0, 0, 0);
      accO[tr] = __builtin_amdgcn_mfma_f32_16x16x32_bf16(a1, bW1, accO[tr], 0, 0, 0);
    }
  }

#pragma unroll
  for (int tr = 0; tr < 4; ++tr)
#pragma unroll
    for (int i = 0; i < 4; ++i)
      spre[(size_t)(b * 64 + tr * 16 + q * 4 + i) * 4096 + m0 + wv * 16 + l] = accO[tr][i];
}

// ---------------------------------------------------------------------------
// Kernel 5: channel attention partial scores. (unchanged)
// ---------------------------------------------------------------------------
__global__ __launch_bounds__(256) void k_ch_scores(
    const float* __restrict__ qk, float* __restrict__ part) {
  int b = blockIdx.y, ch = blockIdx.x;
  const float* q2 = qk + (size_t)(b * 256 + 128) * 4096;
  const float* k2 = qk + (size_t)(b * 256 + 192) * 4096;
  __shared__ float Qs[64][65];
  __shared__ float Ks[64][65];
  int t = threadIdx.x, ti = t >> 4, tj = t & 15;
  float acc[4][4] = {};

  for (int sub = 0; sub < 8; ++sub) {
    int n0 = ch * 512 + sub * 64;
    __syncthreads();
    for (int i = t; i < 4096; i += 256) {
      int r = i >> 6, n = i & 63;
      Qs[r][n] = q2[(size_t)r * 4096 + n0 + n];
      Ks[r][n] = k2[(size_t)r * 4096 + n0 + n];
    }
    __syncthreads();
#pragma unroll
    for (int n = 0; n < 64; ++n) {
      float qa[4], ka[4];
#pragma unroll
      for (int i = 0; i < 4; ++i) qa[i] = Qs[ti * 4 + i][n];
#pragma unroll
      for (int jx = 0; jx < 4; ++jx) ka[jx] = Ks[tj * 4 + jx][n];
#pragma unroll
      for (int i = 0; i < 4; ++i)
#pragma unroll
        for (int jx = 0; jx < 4; ++jx) acc[i][jx] += qa[i] * ka[jx];
    }
  }
#pragma unroll
  for (int i = 0; i < 4; ++i)
#pragma unroll
    for (int jx = 0; jx < 4; ++jx)
      part[(size_t)(b * 8 + ch) * 4096 + (ti * 4 + i) * 64 + tj * 4 + jx] = acc[i][jx];
}

// ---------------------------------------------------------------------------
// Kernel 6: reduce partials + row softmax -> attn2[b][r][s] (unchanged)
// ---------------------------------------------------------------------------
__global__ __launch_bounds__(64) void k_ch_softmax(
    const float* __restrict__ part, float* __restrict__ attn2) {
  int b = blockIdx.x, r = threadIdx.x;
  float v[64];
  float mx = -1e30f;
#pragma unroll
  for (int s = 0; s < 64; ++s) {
    float sum = 0.f;
#pragma unroll
    for (int c = 0; c < 8; ++c)
      sum += part[(size_t)(b * 8 + c) * 4096 + r * 64 + s];
    v[s] = sum;
    mx = fmaxf(mx, sum);
  }
  float den = 0.f;
#pragma unroll
  for (int s = 0; s < 64; ++s) { v[s] = __expf(v[s] - mx); den += v[s]; }
  float inv = 1.0f / den;
#pragma unroll
  for (int s = 0; s < 64; ++s)
    attn2[(size_t)b * 4096 + r * 64 + s] = v[s] * inv;
}

// ---------------------------------------------------------------------------
// Kernel 7: cpre[b][r][n] = sum_s attn2[r,s] * k2[s,n] (unchanged)
// ---------------------------------------------------------------------------
__global__ __launch_bounds__(256) void k_ch_apply(
    const float* __restrict__ qk, const float* __restrict__ attn2,
    float* __restrict__ cpre) {
  int b = blockIdx.y;
  int n = blockIdx.x * 256 + threadIdx.x;
  const float* k2 = qk + (size_t)(b * 256 + 192) * 4096;
  __shared__ float As[64][64];
  int t = threadIdx.x;
  for (int i = t; i < 4096; i += 256) As[i >> 6][i & 63] = attn2[(size_t)b * 4096 + i];
  __syncthreads();

  float acc[64];
#pragma unroll
  for (int r = 0; r < 64; ++r) acc[r] = 0.f;
  for (int s4 = 0; s4 < 64; s4 += 4) {
    float kv0 = k2[(size_t)(s4 + 0) * 4096 + n];
    float kv1 = k2[(size_t)(s4 + 1) * 4096 + n];
    float kv2 = k2[(size_t)(s4 + 2) * 4096 + n];
    float kv3 = k2[(size_t)(s4 + 3) * 4096 + n];
#pragma unroll
    for (int r = 0; r < 64; ++r) {
      float4 w = *reinterpret_cast<const float4*>(&As[r][s4]);
      acc[r] += w.x * kv0 + w.y * kv1 + w.z * kv2 + w.w * kv3;
    }
  }
#pragma unroll
  for (int r = 0; r < 64; ++r)
    cpre[(size_t)(b * 64 + r) * 4096 + n] = acc[r];
}

// ---------------------------------------------------------------------------
// Kernel 9 (MFMA): final fused conv.
// out[b][o][n] = Wf[o][0:64]@spre + Wf[o][64:128]@cpre + bfb[o]
// M=512, K=128, N=4096/batch. Same template as k_gemm_qk_mfma, 4 K-iters.
// ---------------------------------------------------------------------------
__global__ __launch_bounds__(256) void k_final_mfma(
    const float* __restrict__ spre, const float* __restrict__ cpre,
    const u16* __restrict__ Wfb, const float* __restrict__ bfb,
    float* __restrict__ out) {
  int b = blockIdx.z, o0 = blockIdx.y * 128, n0 = blockIdx.x * 128;
  __shared__ u16 Aj[128][40];
  __shared__ u16 Xs[128][40];
  int t = threadIdx.x;
  int wv = t >> 6, lane = t & 63;
  int wr = wv >> 1, wc = wv & 1;
  int q = lane >> 4, l = lane & 15;

  f32x4 acc[4][4];
#pragma unroll
  for (int tr = 0; tr < 4; ++tr)
#pragma unroll
    for (int tc = 0; tc < 4; ++tc) acc[tr][tc] = (f32x4){0.f, 0.f, 0.f, 0.f};

  int xn = t & 31;
  int xs = t >> 5;

  for (int kc = 0; kc < 128; kc += 32) {
    __syncthreads();
    {
      const u32* asrc = reinterpret_cast<const u32*>(Wfb + (size_t)o0 * 128 + kc);
#pragma unroll
      for (int p = 0; p < 8; ++p) {
        int i = p * 256 + t;
        int row = i >> 4, c = i & 15;
        *reinterpret_cast<u32*>(&Aj[row][c * 2]) = asrc[(size_t)row * 64 + c];
      }
    }
    const float* src = (kc < 64) ? spre : cpre;
    int r0 = (kc < 64) ? kc : kc - 64;
    const float* xb = src + (size_t)(b * 64 + r0) * 4096 + n0;
#pragma unroll
    for (int p = 0; p < 8; ++p) {
      int n = xn + 32 * (p >> 1);
      int kp = xs + 8 * (p & 1);
      float v0 = xb[(size_t)(2 * kp) * 4096 + n];
      float v1 = xb[(size_t)(2 * kp + 1) * 4096 + n];
      *reinterpret_cast<u32*>(&Xs[n][kp * 2]) =
          (u32)f2bf(v0) | ((u32)f2bf(v1) << 16);
    }
    __syncthreads();

    short8 af[4], bfr[4];
#pragma unroll
    for (int tr = 0; tr < 4; ++tr)
      af[tr] = *reinterpret_cast<const short8*>(&Aj[wr * 64 + tr * 16 + l][q * 8]);
#pragma unroll
    for (int tc = 0; tc < 4; ++tc)
      bfr[tc] = *reinterpret_cast<const short8*>(&Xs[wc * 64 + tc * 16 + l][q * 8]);
#pragma unroll
    for (int tr = 0; tr < 4; ++tr)
#pragma unroll
      for (int tc = 0; tc < 4; ++tc)
        acc[tr][tc] = __builtin_amdgcn_mfma_f32_16x16x32_bf16(
            af[tr], bfr[tc], acc[tr][tc], 0, 0, 0);
  }

#pragma unroll
  for (int tr = 0; tr < 4; ++tr) {
    int o = o0 + wr * 64 + tr * 16 + q * 4;
    float4 bias = *reinterpret_cast<const float4*>(&bfb[o]);
#pragma unroll
    for (int tc = 0; tc < 4; ++tc) {
      int n = n0 + wc * 64 + tc * 16 + l;
      float* dst = out + (size_t)(b * 512 + o) * 4096 + n;
      dst[0]        = acc[tr][tc][0] + bias.x;
      dst[4096]     = acc[tr][tc][1] + bias.y;
      dst[2 * 4096] = acc[tr][tc][2] + bias.z;
      dst[3 * 4096] = acc[tr][tc][3] + bias.w;
    }
  }
}

// ---------------------------------------------------------------------------
extern "C" void kernel_launch(void* const* d_in, const int* in_sizes, int n_in,
                              void* d_out, int out_size, void* d_ws, size_t ws_size,
                              hipStream_t stream) {
  const float* top  = (const float*)d_in[0];
  const float* bot  = (const float*)d_in[1];
  const float* wt   = (const float*)d_in[2];
  const float* bt   = (const float*)d_in[3];
  const float* wb   = (const float*)d_in[4];
  const float* bb   = (const float*)d_in[5];
  const float* s_w1 = (const float*)d_in[6];
  const float* s_b1 = (const float*)d_in[7];
  const float* s_w2 = (const float*)d_in[8];
  const float* s_b2 = (const float*)d_in[9];
  const float* s_wo = (const float*)d_in[10];
  const float* s_bo = (const float*)d_in[11];
  const float* c_wq = (const float*)d_in[12];
  const float* c_bq = (const float*)d_in[13];
  const float* c_wk = (const float*)d_in[14];
  const float* c_bk = (const float*)d_in[15];
  const float* c_wo = (const float*)d_in[16];
  const float* c_bo = (const float*)d_in[17];
  const float* f_w  = (const float*)d_in[18];
  const float* f_b  = (const float*)d_in[19];
  float* out = (float*)d_out;

  // d_out (64 MB) doubles as scratch until k_final_mfma overwrites it:
  //   [0,32MB)  qk fp32 [8][256][4096]
  //   [32,36MB) q1t bf16 [8][4096][64]
  //   [36,40MB) k1t bf16 [8][4096][64]
  //   [40,44MB) k1d bf16 [8][64][4096]
  char* ob = (char*)d_out;
  float* qk = (float*)ob;
  u16* q1t = (u16*)(ob + 33554432);
  u16* k1t = (u16*)(ob + 37748736);
  u16* k1d = (u16*)(ob + 41943040);

  char* ws = (char*)d_ws;   // ~18.8 MB used
  float* dinv  = (float*)(ws + 0);          // [8][4096]          131,072 B
  float* part  = (float*)(ws + 131072);     // [8][8][64][64]   1,048,576 B
  float* attn2 = (float*)(ws + 1179648);    // [8][64][64]        131,072 B
  float* spre  = (float*)(ws + 1310720);    // [8][64][4096]    8,388,608 B
  float* cpre  = (float*)(ws + 9699328);    // [8][64][4096]    8,388,608 B
  u16*   Wqkb  = (u16*)  (ws + 18087936);   // [256][1024] bf16   524,288 B
  float* bqk   = (float*)(ws + 18612224);   // [256]                1,024 B
  u16*   Wfb   = (u16*)  (ws + 18613248);   // [512][128] bf16    131,072 B
  float* bfb   = (float*)(ws + 18744320);   // [512]                2,048 B

  k_combine_qk<<<256, 256, 0, stream>>>(wt, bt, wb, bb, s_w1, s_b1, s_w2, s_b2,
                                        c_wq, c_bq, c_wk, c_bk, Wqkb, bqk);
  k_combine_f<<<512, 128, 0, stream>>>(f_w, f_b, s_wo, s_bo, c_wo, c_bo, Wfb, bfb);
  k_gemm_qk_mfma<<<dim3(32, 2, 8), 256, 0, stream>>>(top, bot, Wqkb, bqk, qk);
  k_transpose_qk<<<dim3(64, 8), 256, 0, stream>>>(qk, q1t, k1t);
  k_sp_stats_mfma<<<dim3(64, 8), 256, 0, stream>>>(q1t, k1t, dinv);
  k_ch_scores<<<dim3(8, 8), 256, 0, stream>>>(qk, part);
  k_ch_softmax<<<8, 64, 0, stream>>>(part, attn2);
  k_ch_apply<<<dim3(16, 8), 256, 0, stream>>>(qk, attn2, cpre);
  k_scale_k1d<<<512, 256, 0, stream>>>(qk, dinv, k1d);
  k_sp_apply_mfma<<<dim3(64, 8), 256, 0, stream>>>(q1t, k1t, k1d, spre);
  k_final_mfma<<<dim3(32, 4, 8), 256, 0, stream>>>(spre, cpre, Wfb, bfb, out);
}